// Round 1
// baseline (148.404 us; speedup 1.0000x reference)
//
#include <hip/hip_runtime.h>
#include <hip/hip_bf16.h>

// DiffusionGraphConv on MI355X (gfx950), bf16 MFMA pipeline.
//
// Shapes: B=64, N=1024, INPUT_DIM=HID_DIM=64, F=128, SUPPORTS=2, MAXDIFF=2,
// M=5 matrices, OUT=128.
//
// Layouts (all bf16 in d_ws):
//   x0t  [(b*128+f)][n]  "feature-major" (transposed)  -- A-op of x1-GEMM, read by x2 epilogue
//   x?nf [n][(b*128+f)]  "node-first"                  -- A-op rows of final GEMM (r = n*64+b)
//   sup  [s][n][m] bf16
//   w2t  [o][m*128+f] = weight[(f*5+m)*128+o]          -- B^T layout for final GEMM
//
// GEMM orientations (all operands end up k-contiguous, no transposed LDS reads):
//   x1:  Ct[(b,f)][n]   = x0t @ supT   (A=x0t, B^T=sup row-major)   -> x1t natural + x1nf scatter
//   x2:  C[n][(b,f)]    = sup @ x1     (A=sup, B^T=x1t)             -> 2*acc - x0t, store x2nf natural
//   out: C[r=(n,b)][o]  = Xnf @ W2     (A=x?nf, B^T=w2t)            -> +bias, store d_out f32

typedef short bf16x8  __attribute__((ext_vector_type(8)));
typedef short short4v __attribute__((ext_vector_type(4)));
typedef float f32x4   __attribute__((ext_vector_type(4)));

constexpr size_t SZ_MAT  = 8192ull * 1024ull;          // one X matrix (elems)
constexpr size_t OFF_SUP  = 0;                         // 2 * 1M elems
constexpr size_t OFF_X0T  = 2ull * 1024 * 1024;
constexpr size_t OFF_X0NF = OFF_X0T  + SZ_MAT;
constexpr size_t OFF_X1T  = OFF_X0NF + SZ_MAT;         // [s]
constexpr size_t OFF_X1NF = OFF_X1T  + 2 * SZ_MAT;     // [s]
constexpr size_t OFF_X2NF = OFF_X1NF + 2 * SZ_MAT;     // [s]
constexpr size_t OFF_W2T  = OFF_X2NF + 2 * SZ_MAT;     // 640*128

__device__ __forceinline__ unsigned short f2bf(float x) {
  union { float f; unsigned int u; } v; v.f = x;
  unsigned int r = v.u + 0x7fffu + ((v.u >> 16) & 1u);   // RNE
  return (unsigned short)(r >> 16);
}
__device__ __forceinline__ float bf2f(unsigned short b) {
  union { unsigned int u; float f; } v; v.u = ((unsigned int)b) << 16; return v.f;
}

#define GLD16(gp, lp)                                                         \
  __builtin_amdgcn_global_load_lds(                                           \
      (const __attribute__((address_space(1))) unsigned int*)(gp),            \
      (__attribute__((address_space(3))) unsigned int*)(lp), 16, 0, 0)

// ---------------- prep kernels ----------------

__global__ void cvt_sup_kernel(const float* __restrict__ sup,
                               unsigned short* __restrict__ ws) {
  size_t t = (size_t)blockIdx.x * 256 + threadIdx.x;     // < 524288
  const float4* src = (const float4*)sup;
  float4 v = src[t];
  short4v o; o[0] = (short)f2bf(v.x); o[1] = (short)f2bf(v.y);
  o[2] = (short)f2bf(v.z); o[3] = (short)f2bf(v.w);
  *(short4v*)&ws[OFF_SUP + t * 4] = o;
}

__global__ void w2t_kernel(const float* __restrict__ weight,
                           unsigned short* __restrict__ ws) {
  int t = blockIdx.x * 256 + threadIdx.x;                // < 81920
  int o = t / 640, k = t % 640;
  int m = k >> 7, f = k & 127;
  ws[OFF_W2T + t] = f2bf(weight[(f * 5 + m) * 128 + o]);
}

// x0 pack: x0nf direct + x0t via LDS transpose. grid (64 b, 16 ntile, 2 ftile)
__global__ void pack_kernel(const float* __restrict__ inputs,
                            const float* __restrict__ state,
                            unsigned short* __restrict__ ws) {
  int b = blockIdx.x, nt = blockIdx.y, ft = blockIdx.z;
  const float* src = ft ? state : inputs;                // [b][n*64 + fl]
  unsigned short* x0t  = ws + OFF_X0T;
  unsigned short* x0nf = ws + OFF_X0NF;
  __shared__ unsigned short tile[64][65];
  int tl = threadIdx.x; int fl = tl & 63; int nr = tl >> 6;
#pragma unroll 4
  for (int rr = 0; rr < 16; ++rr) {
    int n_loc = rr * 4 + nr;
    float v = src[(size_t)b * 65536 + (size_t)(nt * 64 + n_loc) * 64 + fl];
    unsigned short bv = f2bf(v);
    tile[n_loc][fl] = bv;
    x0nf[(size_t)(nt * 64 + n_loc) * 8192 + b * 128 + ft * 64 + fl] = bv;
  }
  __syncthreads();
#pragma unroll 4
  for (int rr = 0; rr < 16; ++rr) {
    int f_loc = rr * 4 + nr;
    x0t[(size_t)(b * 128 + ft * 64 + f_loc) * 1024 + nt * 64 + fl] = tile[fl][f_loc];
  }
}

// ---------------- GEMM core ----------------
// 128x128 tile, BK=64, 256 threads (4 waves, 2x2), wave tile 64x64 (4x4 frags),
// mfma_f32_16x16x32_bf16, global_load_lds w16, XOR-swizzled LDS (koff ^ (row&7)<<3).

__device__ __forceinline__ size_t xnf_off(int m) {
  switch (m) {
    case 0:  return OFF_X0NF;
    case 1:  return OFF_X1NF;
    case 2:  return OFF_X2NF;
    case 3:  return OFF_X1NF + SZ_MAT;
    default: return OFF_X2NF + SZ_MAT;
  }
}

template <int MODE>
__global__ __launch_bounds__(256)
void gemm_kernel(unsigned short* __restrict__ ws,
                 const float* __restrict__ bias,
                 float* __restrict__ dout) {
  __shared__ short At[128 * 64];
  __shared__ short Bt[128 * 64];

  const int tid = threadIdx.x;
  const int l   = tid & 63;
  const int w   = tid >> 6;
  const int wr  = w >> 1, wc = w & 1;
  const int bm  = blockIdx.x;
  const int bn  = blockIdx.y;
  const int s   = blockIdx.z;

  const unsigned short* A;
  const unsigned short* B;
  int KT;
  if constexpr (MODE == 0) {        // x1 = x0 @ A^T   (rows (b,f), cols n)
    A = ws + OFF_X0T;
    B = ws + OFF_SUP + (size_t)s * 1048576;
    KT = 16;
  } else if constexpr (MODE == 1) { // x2 = A @ x1     (rows n, cols (b,f))
    A = ws + OFF_SUP + (size_t)s * 1048576;
    B = ws + OFF_X1T + (size_t)s * SZ_MAT;
    KT = 16;
  } else {                          // out             (rows r=n*64+b, cols o)
    A = nullptr;
    B = ws + OFF_W2T;
    KT = 10;
  }

  // staging lane constants: chunk covers 8 rows x 64k; lane l -> row chunk*8+l/8,
  // source k pre-swizzled so linear LDS write + swizzled read line up.
  const int subrow = l >> 3;                       // 0..7, == row&7
  const int koff   = (((l & 7) << 3) ^ (subrow << 3));  // elems, 16B units

  f32x4 acc[4][4] = {};

  for (int kt = 0; kt < KT; ++kt) {
    // stage A tile (this wave: chunks w*4 .. w*4+3)
#pragma unroll
    for (int c = 0; c < 4; ++c) {
      int chunk = w * 4 + c;
      int rowl  = chunk * 8 + subrow;
      const unsigned short* gp;
      if constexpr (MODE == 2) {
        int rg = bm * 128 + rowl;                  // r = n*64+b
        const unsigned short* base = ws + xnf_off(kt >> 1);
        gp = base + (size_t)(rg >> 6) * 8192 + (size_t)(rg & 63) * 128 +
             (kt & 1) * 64 + koff;
      } else {
        gp = A + (size_t)(bm * 128 + rowl) * 1024 + kt * 64 + koff;
      }
      GLD16(gp, &At[chunk * 512]);
    }
    // stage B tile (B^T layout: row = output col, k-contiguous)
#pragma unroll
    for (int c = 0; c < 4; ++c) {
      int chunk = w * 4 + c;
      int rowl  = chunk * 8 + subrow;
      const unsigned short* gp;
      if constexpr (MODE == 2) {
        gp = B + (size_t)rowl * 640 + kt * 64 + koff;   // w2t, ldb=640, bn==0
      } else {
        gp = B + (size_t)(bn * 128 + rowl) * 1024 + kt * 64 + koff;
      }
      GLD16(gp, &Bt[chunk * 512]);
    }
    __syncthreads();   // compiler drains vmcnt before barrier

#pragma unroll
    for (int kk = 0; kk < 2; ++kk) {
      bf16x8 af[4], bfr[4];
#pragma unroll
      for (int i = 0; i < 4; ++i) {
        int row = wr * 64 + i * 16 + (l & 15);
        int off = row * 64 + ((kk * 32 + ((l >> 4) << 3)) ^ ((row & 7) << 3));
        af[i] = *(const bf16x8*)&At[off];
      }
#pragma unroll
      for (int j = 0; j < 4; ++j) {
        int row = wc * 64 + j * 16 + (l & 15);
        int off = row * 64 + ((kk * 32 + ((l >> 4) << 3)) ^ ((row & 7) << 3));
        bfr[j] = *(const bf16x8*)&Bt[off];
      }
#pragma unroll
      for (int i = 0; i < 4; ++i)
#pragma unroll
        for (int j = 0; j < 4; ++j)
          acc[i][j] = __builtin_amdgcn_mfma_f32_16x16x32_bf16(af[i], bfr[j],
                                                              acc[i][j], 0, 0, 0);
    }
    __syncthreads();
  }

  // ---------------- epilogues ----------------
  if constexpr (MODE == 0) {
    unsigned short* x1t  = ws + OFF_X1T  + (size_t)s * SZ_MAT;
    unsigned short* x1nf = ws + OFF_X1NF + (size_t)s * SZ_MAT;
#pragma unroll
    for (int i = 0; i < 4; ++i) {
      int rg0 = bm * 128 + wr * 64 + i * 16 + ((l >> 4) << 2);   // (b,f)
#pragma unroll
      for (int j = 0; j < 4; ++j) {
        int cg = bn * 128 + wc * 64 + j * 16 + (l & 15);         // n
        short4v pk;
#pragma unroll
        for (int r = 0; r < 4; ++r) {
          unsigned short bv = f2bf(acc[i][j][r]);
          x1t[(size_t)(rg0 + r) * 1024 + cg] = bv;               // feature-major
          pk[r] = (short)bv;
        }
        *(short4v*)&x1nf[(size_t)cg * 8192 + rg0] = pk;          // node-first
      }
    }
  } else if constexpr (MODE == 1) {
    const unsigned short* x0t = ws + OFF_X0T;
    unsigned short* x2nf = ws + OFF_X2NF + (size_t)s * SZ_MAT;
#pragma unroll
    for (int i = 0; i < 4; ++i) {
      int rg0 = bm * 128 + wr * 64 + i * 16 + ((l >> 4) << 2);   // n
#pragma unroll
      for (int j = 0; j < 4; ++j) {
        int cg = bn * 128 + wc * 64 + j * 16 + (l & 15);         // (b,f)
        short4v x0v = *(const short4v*)&x0t[(size_t)cg * 1024 + rg0];
#pragma unroll
        for (int r = 0; r < 4; ++r) {
          float v = 2.0f * acc[i][j][r] - bf2f((unsigned short)x0v[r]);
          x2nf[(size_t)(rg0 + r) * 8192 + cg] = f2bf(v);
        }
      }
    }
  } else {
#pragma unroll
    for (int i = 0; i < 4; ++i) {
      int rg0 = bm * 128 + wr * 64 + i * 16 + ((l >> 4) << 2);   // r = n*64+b
#pragma unroll
      for (int j = 0; j < 4; ++j) {
        int cg = wc * 64 + j * 16 + (l & 15);                    // o
        float bv = bias[cg];
#pragma unroll
        for (int r = 0; r < 4; ++r) {
          int rg = rg0 + r;
          int drow = ((rg & 63) << 10) | (rg >> 6);              // b*1024 + n
          dout[(size_t)drow * 128 + cg] = acc[i][j][r] + bv;
        }
      }
    }
  }
}

// ---------------- launcher ----------------

extern "C" void kernel_launch(void* const* d_in, const int* in_sizes, int n_in,
                              void* d_out, int out_size, void* d_ws, size_t ws_size,
                              hipStream_t stream) {
  (void)in_sizes; (void)n_in; (void)out_size; (void)ws_size;
  const float* supports = (const float*)d_in[0];
  const float* inputs   = (const float*)d_in[1];
  const float* state    = (const float*)d_in[2];
  const float* weight   = (const float*)d_in[3];
  const float* bias     = (const float*)d_in[4];
  float* out = (float*)d_out;
  unsigned short* ws = (unsigned short*)d_ws;

  cvt_sup_kernel<<<2048, 256, 0, stream>>>(supports, ws);
  w2t_kernel<<<320, 256, 0, stream>>>(weight, ws);
  pack_kernel<<<dim3(64, 16, 2), 256, 0, stream>>>(inputs, state, ws);

  gemm_kernel<0><<<dim3(64, 8, 2), 256, 0, stream>>>(ws, bias, out);   // x1 (both supports)
  gemm_kernel<1><<<dim3(8, 64, 2), 256, 0, stream>>>(ws, bias, out);   // x2 (both supports)
  gemm_kernel<2><<<dim3(512, 1, 1), 256, 0, stream>>>(ws, bias, out);  // final + bias
}

// Round 2
// 142.517 us; speedup vs baseline: 1.0413x; 1.0413x over previous
//
#include <hip/hip_runtime.h>
#include <hip/hip_bf16.h>

// DiffusionGraphConv on MI355X (gfx950), bf16 MFMA pipeline, round 2.
//
// Key restructure: x2 = 2*A*(A*x0) - x0 = (2*A^2 - I)*x0.  Precompute
// Pstack = [A1; 2*A1^2-I; A2; 2*A2^2-I]  (4 x 1024 x 1024 bf16), then all four
// diffusion matrices come from ONE GEMM:
//     Y[(m',n)][(b,f)] = Pstack @ X0      (M=4096, N=8192, K=1024)
// whose natural row-major output IS the node-first layout the final GEMM
// stages from (coalesced stores, no x1 round-trip).
//
// ws layout (bf16 elems):
//   PSTK  4M   [A1 | 2A1^2-I | A2 | 2A2^2-I]   row-major [n][n']
//   SUPT  2M   [A1^T | A2^T]                    (psq B-operand)
//   X0T   8M   [(b*128+f)][n]                   (big-GEMM B^T operand)
//   X0NF  8M   [n][(b*128+f)]                   (final-GEMM A rows, m=0)
//   XNF  32M   [m'-1][n][(b*128+f)]             (big-GEMM output, m'=1..4)
//   W2T  80K   [o][m*128+f] = weight[(f*5+m)*128+o]

typedef short bf16x8  __attribute__((ext_vector_type(8)));
typedef short short4v __attribute__((ext_vector_type(4)));
typedef float f32x4   __attribute__((ext_vector_type(4)));

constexpr size_t MB1    = 1024ull * 1024ull;
constexpr size_t SZ_MAT = 8192ull * 1024ull;
constexpr size_t OFF_PSTK = 0;
constexpr size_t OFF_SUPT = 4 * MB1;
constexpr size_t OFF_X0T  = 6 * MB1;
constexpr size_t OFF_X0NF = OFF_X0T  + SZ_MAT;
constexpr size_t OFF_XNF  = OFF_X0NF + SZ_MAT;
constexpr size_t OFF_W2T  = OFF_XNF  + 4 * SZ_MAT;

__device__ __forceinline__ unsigned short f2bf(float x) {
  union { float f; unsigned int u; } v; v.f = x;
  unsigned int r = v.u + 0x7fffu + ((v.u >> 16) & 1u);   // RNE
  return (unsigned short)(r >> 16);
}
__device__ __forceinline__ float bf2f(unsigned short b) {
  union { unsigned int u; float f; } v; v.u = ((unsigned int)b) << 16; return v.f;
}

#define GLD16(gp, lp)                                                         \
  __builtin_amdgcn_global_load_lds(                                           \
      (const __attribute__((address_space(1))) unsigned int*)(gp),            \
      (__attribute__((address_space(3))) unsigned int*)(lp), 16, 0, 0)

// ---------------- prep kernels ----------------

// f32 supports -> bf16, written into Pstack rows 0 (A1) and 2 (A2).
__global__ void cvt_sup_kernel(const float* __restrict__ sup,
                               unsigned short* __restrict__ ws) {
  size_t t = (size_t)blockIdx.x * 256 + threadIdx.x;     // < 524288
  const float4* src = (const float4*)sup;
  float4 v = src[t];
  size_t e = t * 4;
  size_t s = e >> 20;
  size_t r = e & (MB1 - 1);
  short4v o; o[0] = (short)f2bf(v.x); o[1] = (short)f2bf(v.y);
  o[2] = (short)f2bf(v.z); o[3] = (short)f2bf(v.w);
  *(short4v*)&ws[OFF_PSTK + 2 * s * MB1 + r] = o;
}

// A_s^T for the psq GEMM's B-operand (64x64 LDS tile transpose).
__global__ void sup_t_kernel(unsigned short* __restrict__ ws) {
  int nt = blockIdx.x, mt = blockIdx.y, s = blockIdx.z;
  const unsigned short* A = ws + OFF_PSTK + (size_t)(2 * s) * MB1;
  unsigned short* AT = ws + OFF_SUPT + (size_t)s * MB1;
  __shared__ unsigned short tile[64][65];
  int t = threadIdx.x; int cl = t & 63; int rg = t >> 6;
#pragma unroll 4
  for (int rr = 0; rr < 16; ++rr) {
    int rl = rr * 4 + rg;
    tile[rl][cl] = A[(size_t)(nt * 64 + rl) * 1024 + mt * 64 + cl];
  }
  __syncthreads();
#pragma unroll 4
  for (int rr = 0; rr < 16; ++rr) {
    int ml = rr * 4 + rg;
    AT[(size_t)(mt * 64 + ml) * 1024 + nt * 64 + cl] = tile[cl][ml];
  }
}

__global__ void w2t_kernel(const float* __restrict__ weight,
                           unsigned short* __restrict__ ws) {
  int t = blockIdx.x * 256 + threadIdx.x;                // < 81920
  int o = t / 640, k = t % 640;
  int m = k >> 7, f = k & 127;
  ws[OFF_W2T + t] = f2bf(weight[(f * 5 + m) * 128 + o]);
}

// x0 pack: x0nf direct + x0t via LDS transpose. grid (64 b, 16 ntile, 2 ftile)
__global__ void pack_kernel(const float* __restrict__ inputs,
                            const float* __restrict__ state,
                            unsigned short* __restrict__ ws) {
  int b = blockIdx.x, nt = blockIdx.y, ft = blockIdx.z;
  const float* src = ft ? state : inputs;                // [b][n*64 + fl]
  unsigned short* x0t  = ws + OFF_X0T;
  unsigned short* x0nf = ws + OFF_X0NF;
  __shared__ unsigned short tile[64][65];
  int tl = threadIdx.x; int fl = tl & 63; int nr = tl >> 6;
#pragma unroll 4
  for (int rr = 0; rr < 16; ++rr) {
    int n_loc = rr * 4 + nr;
    float v = src[(size_t)b * 65536 + (size_t)(nt * 64 + n_loc) * 64 + fl];
    unsigned short bv = f2bf(v);
    tile[n_loc][fl] = bv;
    x0nf[(size_t)(nt * 64 + n_loc) * 8192 + b * 128 + ft * 64 + fl] = bv;
  }
  __syncthreads();
#pragma unroll 4
  for (int rr = 0; rr < 16; ++rr) {
    int f_loc = rr * 4 + nr;
    x0t[(size_t)(b * 128 + ft * 64 + f_loc) * 1024 + nt * 64 + fl] = tile[fl][f_loc];
  }
}

// ---------------- GEMM core ----------------
// 128x(32*NJ) tile, BK=64, 256 threads (4 waves, 2x2), wave tile 64x(16*NJ),
// mfma_f32_16x16x32_bf16, global_load_lds w16, XOR-swizzled LDS.
//
// MODE 0: psq   C[n][n'] = A_s @ A_s, epi 2*acc - I -> Pstack rows 1,3 (NJ=2)
// MODE 1: big   Y = Pstack @ X0 (A=Pstack rows, B^T=x0t), XCD-swizzled grid
// MODE 2: final out = Xnf @ W2 + bias -> d_out f32

template <int MODE, int NJ>
__global__ __launch_bounds__(256)
void gemm_kernel(unsigned short* __restrict__ ws,
                 const float* __restrict__ bias,
                 float* __restrict__ dout) {
  __shared__ short At[128 * 64];
  __shared__ short Bt[32 * NJ * 64];

  const int tid = threadIdx.x;
  const int l   = tid & 63;
  const int w   = tid >> 6;
  const int wr  = w >> 1, wc = w & 1;

  int bm, bn, s = 0;
  const unsigned short* A = nullptr;
  const unsigned short* B;
  int KT;
  if constexpr (MODE == 0) {
    bm = blockIdx.x; bn = blockIdx.y; s = blockIdx.z;
    A = ws + OFF_PSTK + (size_t)(2 * s) * MB1;
    B = ws + OFF_SUPT + (size_t)s * MB1;
    KT = 16;
  } else if constexpr (MODE == 1) {
    int bid  = blockIdx.x;
    int tile = ((bid & 7) << 8) | (bid >> 3);   // XCD-chunked: xcd k -> bn slice
    bn = tile >> 5; bm = tile & 31;
    A = ws + OFF_PSTK;
    B = ws + OFF_X0T;
    KT = 16;
  } else {
    bm = blockIdx.x; bn = 0;
    B = ws + OFF_W2T;
    KT = 10;
  }

  // staging: chunk = 8 rows x 64k; lane l -> row chunk*8 + l/8; source k
  // pre-swizzled so linear LDS write + XOR-swizzled read line up.
  const int subrow = l >> 3;
  const int koff   = (((l & 7) << 3) ^ (subrow << 3));

  f32x4 acc[4][NJ] = {};

  for (int kt = 0; kt < KT; ++kt) {
#pragma unroll
    for (int c = 0; c < 4; ++c) {               // A tile: 16 chunks, 4/wave
      int chunk = w * 4 + c;
      int rowl  = chunk * 8 + subrow;
      const unsigned short* gp;
      if constexpr (MODE == 2) {
        int rg = bm * 128 + rowl;               // r = n*64+b
        const unsigned short* base =
            (kt < 2) ? (ws + OFF_X0NF)
                     : (ws + OFF_XNF + (size_t)((kt >> 1) - 1) * SZ_MAT);
        gp = base + (size_t)(rg >> 6) * 8192 + (size_t)(rg & 63) * 128 +
             (kt & 1) * 64 + koff;
      } else {
        gp = A + (size_t)(bm * 128 + rowl) * 1024 + kt * 64 + koff;
      }
      GLD16(gp, &At[chunk * 512]);
    }
#pragma unroll
    for (int c = 0; c < NJ; ++c) {              // B tile: 4*NJ chunks, NJ/wave
      int chunk = w * NJ + c;
      int rowl  = chunk * 8 + subrow;
      const unsigned short* gp;
      if constexpr (MODE == 2) {
        gp = B + (size_t)rowl * 640 + kt * 64 + koff;       // w2t, ldb=640
      } else {
        gp = B + (size_t)(bn * (32 * NJ) + rowl) * 1024 + kt * 64 + koff;
      }
      GLD16(gp, &Bt[chunk * 512]);
    }
    __syncthreads();

#pragma unroll
    for (int kk = 0; kk < 2; ++kk) {
      bf16x8 af[4], bfr[NJ];
#pragma unroll
      for (int i = 0; i < 4; ++i) {
        int row = wr * 64 + i * 16 + (l & 15);
        int off = row * 64 + ((kk * 32 + ((l >> 4) << 3)) ^ ((row & 7) << 3));
        af[i] = *(const bf16x8*)&At[off];
      }
#pragma unroll
      for (int j = 0; j < NJ; ++j) {
        int row = wc * (16 * NJ) + j * 16 + (l & 15);
        int off = row * 64 + ((kk * 32 + ((l >> 4) << 3)) ^ ((row & 7) << 3));
        bfr[j] = *(const bf16x8*)&Bt[off];
      }
#pragma unroll
      for (int i = 0; i < 4; ++i)
#pragma unroll
        for (int j = 0; j < NJ; ++j)
          acc[i][j] = __builtin_amdgcn_mfma_f32_16x16x32_bf16(af[i], bfr[j],
                                                              acc[i][j], 0, 0, 0);
    }
    __syncthreads();
  }

  // ---------------- epilogues ----------------
  if constexpr (MODE == 0) {
    unsigned short* P = ws + OFF_PSTK + (size_t)(2 * s + 1) * MB1;
#pragma unroll
    for (int i = 0; i < 4; ++i) {
      int rg0 = bm * 128 + wr * 64 + i * 16 + ((l >> 4) << 2);
#pragma unroll
      for (int j = 0; j < NJ; ++j) {
        int cg = bn * (32 * NJ) + wc * (16 * NJ) + j * 16 + (l & 15);
#pragma unroll
        for (int r = 0; r < 4; ++r) {
          int rg = rg0 + r;
          float v = 2.0f * acc[i][j][r] - (rg == cg ? 1.0f : 0.0f);
          P[(size_t)rg * 1024 + cg] = f2bf(v);
        }
      }
    }
  } else if constexpr (MODE == 1) {
    unsigned short* Y = ws + OFF_XNF;           // [4096][8192] row-major
#pragma unroll
    for (int i = 0; i < 4; ++i) {
      int rg0 = bm * 128 + wr * 64 + i * 16 + ((l >> 4) << 2);
#pragma unroll
      for (int j = 0; j < NJ; ++j) {
        int cg = bn * 128 + wc * 64 + j * 16 + (l & 15);
#pragma unroll
        for (int r = 0; r < 4; ++r)
          Y[(size_t)(rg0 + r) * 8192 + cg] = f2bf(acc[i][j][r]);
      }
    }
  } else {
#pragma unroll
    for (int i = 0; i < 4; ++i) {
      int rg0 = bm * 128 + wr * 64 + i * 16 + ((l >> 4) << 2);   // r = n*64+b
#pragma unroll
      for (int j = 0; j < NJ; ++j) {
        int cg = wc * 64 + j * 16 + (l & 15);                    // o
        float bv = bias[cg];
#pragma unroll
        for (int r = 0; r < 4; ++r) {
          int rg = rg0 + r;
          int drow = ((rg & 63) << 10) | (rg >> 6);              // b*1024 + n
          dout[(size_t)drow * 128 + cg] = acc[i][j][r] + bv;
        }
      }
    }
  }
}

// ---------------- launcher ----------------

extern "C" void kernel_launch(void* const* d_in, const int* in_sizes, int n_in,
                              void* d_out, int out_size, void* d_ws, size_t ws_size,
                              hipStream_t stream) {
  (void)in_sizes; (void)n_in; (void)out_size; (void)ws_size;
  const float* supports = (const float*)d_in[0];
  const float* inputs   = (const float*)d_in[1];
  const float* state    = (const float*)d_in[2];
  const float* weight   = (const float*)d_in[3];
  const float* bias     = (const float*)d_in[4];
  float* out = (float*)d_out;
  unsigned short* ws = (unsigned short*)d_ws;

  cvt_sup_kernel<<<2048, 256, 0, stream>>>(supports, ws);
  sup_t_kernel<<<dim3(16, 16, 2), 256, 0, stream>>>(ws);
  w2t_kernel<<<320, 256, 0, stream>>>(weight, ws);
  pack_kernel<<<dim3(64, 16, 2), 256, 0, stream>>>(inputs, state, ws);

  gemm_kernel<0, 2><<<dim3(8, 16, 2), 256, 0, stream>>>(ws, bias, out);  // P1,P3
  gemm_kernel<1, 4><<<2048, 256, 0, stream>>>(ws, bias, out);            // Y = Pstack @ X0
  gemm_kernel<2, 4><<<512, 256, 0, stream>>>(ws, bias, out);             // out + bias
}